// Round 2
// baseline (292.308 us; speedup 1.0000x reference)
//
#include <hip/hip_runtime.h>

constexpr int H  = 256;
constexpr int H2 = 128;
constexpr int N  = 1024;
constexpr int T  = 12;
constexpr int B  = 4;
constexpr int M  = B * N; // 4096 rows total

// ---------------- k0: fold Wb into W2o ------------------------------------
__global__ void fold_wb_kernel(const float* __restrict__ W2o,
                               const float* __restrict__ b2o,
                               const float* __restrict__ Wb,
                               float* __restrict__ W2of,
                               float* __restrict__ b2of) {
    __shared__ float row[H2];
    const int i = blockIdx.x;            // 0..H-1: rows of W2o; i==H: b2o row
    const int j = threadIdx.x;           // 0..127
    const float* src = (i < H) ? (W2o + i * H2) : b2o;
    row[j] = src[j];
    __syncthreads();
    float acc = 0.f;
#pragma unroll 8
    for (int k = 0; k < H2; ++k) acc = fmaf(row[k], Wb[k * H2 + j], acc);
    if (i < H) W2of[i * H2 + j] = acc;
    else       b2of[j] = acc;
}

// ---------------- shared GEMM tile body -----------------------------------
// 128-row x NT-col tile, 256 threads, 8x(NT/16) per-thread micro-tile split
// into 2x(NT/64) sub-blocks of 4x4 at offsets {0,64} so LDS reads stay
// broadcast/contiguous and global stores are dense 256B runs.
// A: row-major, lda; W: row-major KxN (pre-offset to col block), ldw.
// C pre-offset to (row0, col block).
template<int NT, bool RELU>
__device__ __forceinline__ void gemm_body(
    const float* __restrict__ A, int lda,
    const float* __restrict__ W, int ldw,
    const float* __restrict__ bias,
    float* __restrict__ C, int ldc,
    int K)
{
    constexpr int BK = 32;
    constexpr int JH = NT / 64;
    __shared__ float As[BK][132];       // [k][row], transposed A tile
    __shared__ float Ws[BK][NT + 4];    // [k][col]

    const int tid = threadIdx.x;
    const int tx = tid & 15;
    const int ty = tid >> 4;

    float acc[2][JH][4][4] = {};

    for (int kt = 0; kt < K; kt += BK) {
        // stage A (128 rows x BK) -> transposed
#pragma unroll
        for (int p = 0; p < 4; ++p) {
            const int idx = tid + p * 256;
            const int r  = idx >> 3;       // /(BK/4)
            const int c4 = idx & 7;
            const float4 v = *(const float4*)(A + (size_t)r * lda + kt + 4 * c4);
            As[4 * c4 + 0][r] = v.x;
            As[4 * c4 + 1][r] = v.y;
            As[4 * c4 + 2][r] = v.z;
            As[4 * c4 + 3][r] = v.w;
        }
        // stage W (BK x NT), K-major already
#pragma unroll
        for (int p = 0; p < BK * NT / 4 / 256; ++p) {
            const int idx = tid + p * 256;
            const int k  = idx / (NT / 4);
            const int c4 = idx % (NT / 4);
            *(float4*)&Ws[k][4 * c4] =
                *(const float4*)(W + (size_t)(kt + k) * ldw + 4 * c4);
        }
        __syncthreads();
#pragma unroll
        for (int k = 0; k < BK; ++k) {
            const float4 aL = *(const float4*)&As[k][4 * ty];
            const float4 aH = *(const float4*)&As[k][64 + 4 * ty];
            const float a[2][4] = {{aL.x, aL.y, aL.z, aL.w},
                                   {aH.x, aH.y, aH.z, aH.w}};
            float b[JH][4];
#pragma unroll
            for (int jh = 0; jh < JH; ++jh) {
                const float4 bv = *(const float4*)&Ws[k][64 * jh + 4 * tx];
                b[jh][0] = bv.x; b[jh][1] = bv.y; b[jh][2] = bv.z; b[jh][3] = bv.w;
            }
#pragma unroll
            for (int ih = 0; ih < 2; ++ih)
#pragma unroll
                for (int jh = 0; jh < JH; ++jh)
#pragma unroll
                    for (int i = 0; i < 4; ++i)
#pragma unroll
                        for (int j = 0; j < 4; ++j)
                            acc[ih][jh][i][j] =
                                fmaf(a[ih][i], b[jh][j], acc[ih][jh][i][j]);
        }
        __syncthreads();
    }

#pragma unroll
    for (int jh = 0; jh < JH; ++jh) {
        const float4 b4 = *(const float4*)(bias + 64 * jh + 4 * tx);
        const float bj[4] = {b4.x, b4.y, b4.z, b4.w};
#pragma unroll
        for (int ih = 0; ih < 2; ++ih)
#pragma unroll
            for (int i = 0; i < 4; ++i) {
                float4 o;
                float v0 = acc[ih][jh][i][0] + bj[0];
                float v1 = acc[ih][jh][i][1] + bj[1];
                float v2 = acc[ih][jh][i][2] + bj[2];
                float v3 = acc[ih][jh][i][3] + bj[3];
                if (RELU) {
                    v0 = fmaxf(v0, 0.f); v1 = fmaxf(v1, 0.f);
                    v2 = fmaxf(v2, 0.f); v3 = fmaxf(v3, 0.f);
                }
                o.x = v0; o.y = v1; o.z = v2; o.w = v3;
                *(float4*)(C + (size_t)(64 * ih + 4 * ty + i) * ldc
                             + 64 * jh + 4 * tx) = o;
            }
    }
}

// ---------------- k1: h = relu(x @ [W1o|W1d] + [b1o|b1d]) -------------------
// grid (8, 32): bx -> 64-col block of the 512-wide fused output
__global__ __launch_bounds__(256) void enc1_kernel(
    const float* __restrict__ x,
    const float* __restrict__ W1o, const float* __restrict__ W1d,
    const float* __restrict__ b1o, const float* __restrict__ b1d,
    float* __restrict__ h)
{
    const int bx = blockIdx.x;
    const int row0 = blockIdx.y * 128;
    const float* W    = (bx < 4) ? W1o : W1d;
    const float* bias = (bx < 4) ? b1o : b1d;
    const int wcol0 = (bx & 3) * 64;
    gemm_body<64, true>(x + (size_t)row0 * H, H,
                        W + wcol0, H,
                        bias + wcol0,
                        h + (size_t)row0 * 512 + bx * 64, 512,
                        H);
}

// ---------------- k2: oW = h_o@W2of+b2of ; d = h_d@W2d+b2d ------------------
// grid (2, 32, 2): z = branch
__global__ __launch_bounds__(256) void enc2_kernel(
    const float* __restrict__ h,
    const float* __restrict__ W2of, const float* __restrict__ b2of,
    const float* __restrict__ W2d,  const float* __restrict__ b2d,
    float* __restrict__ oW, float* __restrict__ dd)
{
    const int z = blockIdx.z;
    const int row0 = blockIdx.y * 128;
    const int wcol0 = blockIdx.x * 64;
    const float* A    = h + (size_t)row0 * 512 + z * 256;
    const float* W    = z ? W2d : W2of;
    const float* bias = z ? b2d : b2of;
    float*       C    = (z ? dd : oW) + (size_t)row0 * H2 + wcol0;
    gemm_body<64, false>(A, 512, W + wcol0, H2, bias + wcol0, C, H2, H);
}

// ---------------- k3: scores + fused horizon expansion ----------------------
// 128x128 score tile per block, grid (8, 8, 4). K = H2 = 128.
__global__ __launch_bounds__(256) void scores_expand_kernel(
    const float* __restrict__ oW, const float* __restrict__ dd,
    const float* __restrict__ bbp, const float* __restrict__ wh,
    const float* __restrict__ bh, float* __restrict__ out)
{
    constexpr int BK = 32;
    __shared__ float As[BK][132];  // [k][i-row]
    __shared__ float Bs[BK][132];  // [k][j-row]

    const int tid = threadIdx.x;
    const int tx = tid & 15;
    const int ty = tid >> 4;
    const int b  = blockIdx.z;
    const int i0 = blockIdx.y * 128;
    const int j0 = blockIdx.x * 128;
    const float* Ab = oW + (size_t)b * N * H2 + (size_t)i0 * H2;
    const float* Bb = dd + (size_t)b * N * H2 + (size_t)j0 * H2;

    float acc[2][2][4][4] = {};

    for (int kt = 0; kt < H2; kt += BK) {
#pragma unroll
        for (int p = 0; p < 4; ++p) {
            const int idx = tid + p * 256;
            const int r  = idx >> 3;
            const int c4 = idx & 7;
            const float4 v = *(const float4*)(Ab + (size_t)r * H2 + kt + 4 * c4);
            As[4 * c4 + 0][r] = v.x;
            As[4 * c4 + 1][r] = v.y;
            As[4 * c4 + 2][r] = v.z;
            As[4 * c4 + 3][r] = v.w;
            const float4 w = *(const float4*)(Bb + (size_t)r * H2 + kt + 4 * c4);
            Bs[4 * c4 + 0][r] = w.x;
            Bs[4 * c4 + 1][r] = w.y;
            Bs[4 * c4 + 2][r] = w.z;
            Bs[4 * c4 + 3][r] = w.w;
        }
        __syncthreads();
#pragma unroll
        for (int k = 0; k < BK; ++k) {
            const float4 aL = *(const float4*)&As[k][4 * ty];
            const float4 aH = *(const float4*)&As[k][64 + 4 * ty];
            const float4 bL = *(const float4*)&Bs[k][4 * tx];
            const float4 bH = *(const float4*)&Bs[k][64 + 4 * tx];
            const float a[2][4] = {{aL.x, aL.y, aL.z, aL.w},
                                   {aH.x, aH.y, aH.z, aH.w}};
            const float bb2[2][4] = {{bL.x, bL.y, bL.z, bL.w},
                                     {bH.x, bH.y, bH.z, bH.w}};
#pragma unroll
            for (int ih = 0; ih < 2; ++ih)
#pragma unroll
                for (int jh = 0; jh < 2; ++jh)
#pragma unroll
                    for (int i = 0; i < 4; ++i)
#pragma unroll
                        for (int j = 0; j < 4; ++j)
                            acc[ih][jh][i][j] =
                                fmaf(a[ih][i], bb2[jh][j], acc[ih][jh][i][j]);
        }
        __syncthreads();
    }

    const float bbv = bbp[0];
#pragma unroll
    for (int ih = 0; ih < 2; ++ih)
#pragma unroll
        for (int jh = 0; jh < 2; ++jh)
#pragma unroll
            for (int i = 0; i < 4; ++i)
#pragma unroll
                for (int j = 0; j < 4; ++j)
                    acc[ih][jh][i][j] += bbv;

    float whr[T], bhr[T];
#pragma unroll
    for (int t = 0; t < T; ++t) { whr[t] = wh[t]; bhr[t] = bh[t]; }

    // out[((b*T + t)*N + i)*N + j]; stores are dense 256B runs per (t,ih,i)
#pragma unroll
    for (int t = 0; t < T; ++t) {
        float* ob = out + ((size_t)(b * T + t) * N + i0 + 4 * ty) * N + j0 + 4 * tx;
#pragma unroll
        for (int ih = 0; ih < 2; ++ih)
#pragma unroll
            for (int i = 0; i < 4; ++i) {
#pragma unroll
                for (int jh = 0; jh < 2; ++jh) {
                    float4 o;
                    o.x = fmaxf(fmaf(acc[ih][jh][i][0], whr[t], bhr[t]), 0.f);
                    o.y = fmaxf(fmaf(acc[ih][jh][i][1], whr[t], bhr[t]), 0.f);
                    o.z = fmaxf(fmaf(acc[ih][jh][i][2], whr[t], bhr[t]), 0.f);
                    o.w = fmaxf(fmaf(acc[ih][jh][i][3], whr[t], bhr[t]), 0.f);
                    *(float4*)(ob + (size_t)(64 * ih + i) * N + 64 * jh) = o;
                }
            }
    }
}

extern "C" void kernel_launch(void* const* d_in, const int* in_sizes, int n_in,
                              void* d_out, int out_size, void* d_ws, size_t ws_size,
                              hipStream_t stream) {
    const float* x   = (const float*)d_in[0];
    const float* W1o = (const float*)d_in[1];
    const float* b1o = (const float*)d_in[2];
    const float* W2o = (const float*)d_in[3];
    const float* b2o = (const float*)d_in[4];
    const float* W1d = (const float*)d_in[5];
    const float* b1d = (const float*)d_in[6];
    const float* W2d = (const float*)d_in[7];
    const float* b2d = (const float*)d_in[8];
    const float* Wb  = (const float*)d_in[9];
    const float* bb  = (const float*)d_in[10];
    const float* wh  = (const float*)d_in[11];
    const float* bh  = (const float*)d_in[12];
    float* out = (float*)d_out;

    float* ws   = (float*)d_ws;
    float* W2of = ws;                         // H*H2
    float* b2of = W2of + H * H2;              // H2
    float* oW   = b2of + H2;                  // M*H2
    float* dd   = oW + (size_t)M * H2;        // M*H2
    float* h    = dd + (size_t)M * H2;        // M*512 (o cols 0..255 | d cols 256..511)

    fold_wb_kernel<<<H + 1, H2, 0, stream>>>(W2o, b2o, Wb, W2of, b2of);

    enc1_kernel<<<dim3(8, M / 128), 256, 0, stream>>>(x, W1o, W1d, b1o, b1d, h);

    enc2_kernel<<<dim3(2, M / 128, 2), 256, 0, stream>>>(h, W2of, b2of, W2d, b2d, oW, dd);

    scores_expand_kernel<<<dim3(N / 128, N / 128, B), 256, 0, stream>>>(
        oW, dd, bb, wh, bh, out);
}

// Round 3
// 282.501 us; speedup vs baseline: 1.0347x; 1.0347x over previous
//
#include <hip/hip_runtime.h>

constexpr int H  = 256;
constexpr int H2 = 128;
constexpr int N  = 1024;
constexpr int T  = 12;
constexpr int B  = 4;
constexpr int M  = B * N; // 4096 rows total

// ---------------- k0: fold Wb into W2o ------------------------------------
__global__ void fold_wb_kernel(const float* __restrict__ W2o,
                               const float* __restrict__ b2o,
                               const float* __restrict__ Wb,
                               float* __restrict__ W2of,
                               float* __restrict__ b2of) {
    __shared__ float row[H2];
    const int i = blockIdx.x;            // 0..H-1: rows of W2o; i==H: b2o row
    const int j = threadIdx.x;           // 0..127
    const float* src = (i < H) ? (W2o + i * H2) : b2o;
    row[j] = src[j];
    __syncthreads();
    float acc = 0.f;
#pragma unroll 8
    for (int k = 0; k < H2; ++k) acc = fmaf(row[k], Wb[k * H2 + j], acc);
    if (i < H) W2of[i * H2 + j] = acc;
    else       b2of[j] = acc;
}

// ---------------- shared 64x64 GEMM tile body, BK=64, reg-pipelined ---------
// 256 threads, 4x4 micro-tile. LDS [k][row]/[k][col] so the inner loop is
// 2x ds_read_b128 + 16 v_fma_f32 per k. Next tile's global loads are issued
// right after the "LDS ready" barrier so they drain during compute (the
// barrier's vmcnt(0) then lands a full compute-phase later).
template<bool RELU>
__device__ __forceinline__ void gemm_body(
    const float* __restrict__ A, int lda,
    const float* __restrict__ W, int ldw,      // pre-offset to col block
    const float* __restrict__ bias,            // pre-offset to col block
    float* __restrict__ C, int ldc,            // pre-offset to (row0, col block)
    int K)
{
    constexpr int BK = 64;
    __shared__ float As[BK][68];   // [k][row]
    __shared__ float Ws[BK][68];   // [k][col]

    const int tid = threadIdx.x;
    const int tx = tid & 15;
    const int ty = tid >> 4;

    float4 aR[4], wR[4];
    // prologue: load tile 0 into regs
#pragma unroll
    for (int p = 0; p < 4; ++p) {
        const int idx = tid + p * 256;
        const int r  = idx >> 4;          // A row / W k-row
        const int c4 = idx & 15;
        aR[p] = *(const float4*)(A + (size_t)r * lda + 4 * c4);
        wR[p] = *(const float4*)(W + (size_t)r * ldw + 4 * c4);
    }

    float acc[4][4] = {};

    const int NK = K / BK;
    for (int t = 0; t < BK * NK; t += BK) {
        if (t) __syncthreads();           // previous compute done with LDS
        // regs -> LDS
#pragma unroll
        for (int p = 0; p < 4; ++p) {
            const int idx = tid + p * 256;
            const int r  = idx >> 4;
            const int c4 = idx & 15;
            As[4 * c4 + 0][r] = aR[p].x;
            As[4 * c4 + 1][r] = aR[p].y;
            As[4 * c4 + 2][r] = aR[p].z;
            As[4 * c4 + 3][r] = aR[p].w;
            *(float4*)&Ws[r][4 * c4] = wR[p];
        }
        __syncthreads();                  // LDS ready
        // prefetch next tile into regs (drains during compute below)
        if (t + BK < K) {
#pragma unroll
            for (int p = 0; p < 4; ++p) {
                const int idx = tid + p * 256;
                const int r  = idx >> 4;
                const int c4 = idx & 15;
                aR[p] = *(const float4*)(A + (size_t)r * lda + t + BK + 4 * c4);
                wR[p] = *(const float4*)(W + (size_t)(t + BK + r) * ldw + 4 * c4);
            }
        }
#pragma unroll
        for (int k = 0; k < BK; ++k) {
            const float4 a4 = *(const float4*)&As[k][4 * ty];
            const float4 b4 = *(const float4*)&Ws[k][4 * tx];
            const float a[4] = {a4.x, a4.y, a4.z, a4.w};
            const float b[4] = {b4.x, b4.y, b4.z, b4.w};
#pragma unroll
            for (int i = 0; i < 4; ++i)
#pragma unroll
                for (int j = 0; j < 4; ++j)
                    acc[i][j] = fmaf(a[i], b[j], acc[i][j]);
        }
    }

    const float4 b4 = *(const float4*)(bias + 4 * tx);
    const float bj[4] = {b4.x, b4.y, b4.z, b4.w};
#pragma unroll
    for (int i = 0; i < 4; ++i) {
        float v0 = acc[i][0] + bj[0];
        float v1 = acc[i][1] + bj[1];
        float v2 = acc[i][2] + bj[2];
        float v3 = acc[i][3] + bj[3];
        if (RELU) {
            v0 = fmaxf(v0, 0.f); v1 = fmaxf(v1, 0.f);
            v2 = fmaxf(v2, 0.f); v3 = fmaxf(v3, 0.f);
        }
        float4 o; o.x = v0; o.y = v1; o.z = v2; o.w = v3;
        *(float4*)(C + (size_t)(4 * ty + i) * ldc + 4 * tx) = o;
    }
}

// ---------------- k1: h = relu(x @ [W1o|W1d] + [b1o|b1d]) -------------------
// grid (8, 64) = 512 blocks: bx>>2 = branch, (bx&3)*64 = weight col block
__global__ __launch_bounds__(256) void enc1_kernel(
    const float* __restrict__ x,
    const float* __restrict__ W1o, const float* __restrict__ W1d,
    const float* __restrict__ b1o, const float* __restrict__ b1d,
    float* __restrict__ h)
{
    const int bx = blockIdx.x;
    const int row0 = blockIdx.y * 64;
    const float* W    = (bx < 4) ? W1o : W1d;
    const float* bias = (bx < 4) ? b1o : b1d;
    const int wcol0 = (bx & 3) * 64;
    gemm_body<true>(x + (size_t)row0 * H, H,
                    W + wcol0, H,
                    bias + wcol0,
                    h + (size_t)row0 * 512 + bx * 64, 512,
                    H);
}

// ---------------- k2: oW = h_o@W2of+b2of ; d = h_d@W2d+b2d ------------------
// grid (4, 64) = 256 blocks: bx>>1 = branch, (bx&1)*64 = col block
__global__ __launch_bounds__(256) void enc2_kernel(
    const float* __restrict__ h,
    const float* __restrict__ W2of, const float* __restrict__ b2of,
    const float* __restrict__ W2d,  const float* __restrict__ b2d,
    float* __restrict__ oW, float* __restrict__ dd)
{
    const int bx = blockIdx.x;
    const int z = bx >> 1;
    const int row0 = blockIdx.y * 64;
    const int wcol0 = (bx & 1) * 64;
    const float* A    = h + (size_t)row0 * 512 + z * 256;
    const float* W    = (z ? W2d : W2of) + wcol0;
    const float* bias = (z ? b2d : b2of) + wcol0;
    float*       C    = (z ? dd : oW) + (size_t)row0 * H2 + wcol0;
    gemm_body<false>(A, 512, W, H2, bias, C, H2, H);
}

// ---------------- k3: scores + fused horizon expansion ----------------------
// 64x64 score tile per block, grid (16, 16, 4) = 1024 blocks (4/CU, 16 w/CU).
// K = H2 = 128, BK = 64, reg-pipelined A and B (both transposed-scattered).
__global__ __launch_bounds__(256) void scores_expand_kernel(
    const float* __restrict__ oW, const float* __restrict__ dd,
    const float* __restrict__ bbp, const float* __restrict__ wh,
    const float* __restrict__ bh, float* __restrict__ out)
{
    constexpr int BK = 64;
    __shared__ float As[BK][68];  // [k][i-row]
    __shared__ float Bs[BK][68];  // [k][j-row]

    const int tid = threadIdx.x;
    const int tx = tid & 15;
    const int ty = tid >> 4;
    const int b  = blockIdx.z;
    const int i0 = blockIdx.y * 64;
    const int j0 = blockIdx.x * 64;
    const float* Ab = oW + (size_t)b * N * H2 + (size_t)i0 * H2;
    const float* Bb = dd + (size_t)b * N * H2 + (size_t)j0 * H2;

    float4 aR[4], bR[4];
#pragma unroll
    for (int p = 0; p < 4; ++p) {
        const int idx = tid + p * 256;
        const int r  = idx >> 4;
        const int c4 = idx & 15;
        aR[p] = *(const float4*)(Ab + (size_t)r * H2 + 4 * c4);
        bR[p] = *(const float4*)(Bb + (size_t)r * H2 + 4 * c4);
    }

    float acc[4][4] = {};

    for (int t = 0; t < H2; t += BK) {
        if (t) __syncthreads();
#pragma unroll
        for (int p = 0; p < 4; ++p) {
            const int idx = tid + p * 256;
            const int r  = idx >> 4;
            const int c4 = idx & 15;
            As[4 * c4 + 0][r] = aR[p].x;
            As[4 * c4 + 1][r] = aR[p].y;
            As[4 * c4 + 2][r] = aR[p].z;
            As[4 * c4 + 3][r] = aR[p].w;
            Bs[4 * c4 + 0][r] = bR[p].x;
            Bs[4 * c4 + 1][r] = bR[p].y;
            Bs[4 * c4 + 2][r] = bR[p].z;
            Bs[4 * c4 + 3][r] = bR[p].w;
        }
        __syncthreads();
        if (t + BK < H2) {
#pragma unroll
            for (int p = 0; p < 4; ++p) {
                const int idx = tid + p * 256;
                const int r  = idx >> 4;
                const int c4 = idx & 15;
                aR[p] = *(const float4*)(Ab + (size_t)r * H2 + t + BK + 4 * c4);
                bR[p] = *(const float4*)(Bb + (size_t)r * H2 + t + BK + 4 * c4);
            }
        }
#pragma unroll
        for (int k = 0; k < BK; ++k) {
            const float4 a4 = *(const float4*)&As[k][4 * ty];
            const float4 b4 = *(const float4*)&Bs[k][4 * tx];
            const float a[4] = {a4.x, a4.y, a4.z, a4.w};
            const float bf[4] = {b4.x, b4.y, b4.z, b4.w};
#pragma unroll
            for (int i = 0; i < 4; ++i)
#pragma unroll
                for (int j = 0; j < 4; ++j)
                    acc[i][j] = fmaf(a[i], bf[j], acc[i][j]);
        }
    }

    // epilogue-only scalar reads keep VGPR pressure off the main loop
    const float bbv = bbp[0];
#pragma unroll
    for (int i = 0; i < 4; ++i)
#pragma unroll
        for (int j = 0; j < 4; ++j)
            acc[i][j] += bbv;

    // out[((b*T + t)*N + i)*N + j]; each store row is a dense 256B run
#pragma unroll
    for (int t = 0; t < T; ++t) {
        const float w = wh[t];
        const float bhv = bh[t];
        float* ob = out + ((size_t)(b * T + t) * N + i0 + 4 * ty) * N + j0 + 4 * tx;
#pragma unroll
        for (int i = 0; i < 4; ++i) {
            float4 o;
            o.x = fmaxf(fmaf(acc[i][0], w, bhv), 0.f);
            o.y = fmaxf(fmaf(acc[i][1], w, bhv), 0.f);
            o.z = fmaxf(fmaf(acc[i][2], w, bhv), 0.f);
            o.w = fmaxf(fmaf(acc[i][3], w, bhv), 0.f);
            *(float4*)(ob + (size_t)i * N) = o;
        }
    }
}

extern "C" void kernel_launch(void* const* d_in, const int* in_sizes, int n_in,
                              void* d_out, int out_size, void* d_ws, size_t ws_size,
                              hipStream_t stream) {
    const float* x   = (const float*)d_in[0];
    const float* W1o = (const float*)d_in[1];
    const float* b1o = (const float*)d_in[2];
    const float* W2o = (const float*)d_in[3];
    const float* b2o = (const float*)d_in[4];
    const float* W1d = (const float*)d_in[5];
    const float* b1d = (const float*)d_in[6];
    const float* W2d = (const float*)d_in[7];
    const float* b2d = (const float*)d_in[8];
    const float* Wb  = (const float*)d_in[9];
    const float* bb  = (const float*)d_in[10];
    const float* wh  = (const float*)d_in[11];
    const float* bh  = (const float*)d_in[12];
    float* out = (float*)d_out;

    float* ws   = (float*)d_ws;
    float* W2of = ws;                         // H*H2
    float* b2of = W2of + H * H2;              // H2
    float* oW   = b2of + H2;                  // M*H2
    float* dd   = oW + (size_t)M * H2;        // M*H2
    float* h    = dd + (size_t)M * H2;        // M*512 (o cols 0..255 | d 256..511)

    fold_wb_kernel<<<H + 1, H2, 0, stream>>>(W2o, b2o, Wb, W2of, b2of);

    enc1_kernel<<<dim3(8, M / 64), 256, 0, stream>>>(x, W1o, W1d, b1o, b1d, h);

    enc2_kernel<<<dim3(4, M / 64), 256, 0, stream>>>(h, W2of, b2of, W2d, b2d, oW, dd);

    scores_expand_kernel<<<dim3(N / 64, N / 64, B), 256, 0, stream>>>(
        oW, dd, bb, wh, bh, out);
}

// Round 4
// 250.674 us; speedup vs baseline: 1.1661x; 1.1270x over previous
//
#include <hip/hip_runtime.h>
#include <hip/hip_bf16.h>

constexpr int H  = 256;
constexpr int H2 = 128;
constexpr int N  = 1024;
constexpr int T  = 12;
constexpr int B  = 4;
constexpr int M  = B * N; // 4096 rows total

using short8 = __attribute__((ext_vector_type(8))) short;
using f32x4  = __attribute__((ext_vector_type(4))) float;

// fp32 -> bf16 bits, round-to-nearest-even
__device__ __forceinline__ unsigned short f2bf(float f) {
    union { float f; unsigned int u; } v; v.f = f;
    unsigned int u = v.u;
    u += 0x7FFFu + ((u >> 16) & 1u);
    return (unsigned short)(u >> 16);
}

// ---------------- k0: fold Wb into W2o (fp32, tiny) -------------------------
__global__ void fold_wb_kernel(const float* __restrict__ W2o,
                               const float* __restrict__ b2o,
                               const float* __restrict__ Wb,
                               float* __restrict__ W2of,
                               float* __restrict__ b2of) {
    __shared__ float row[H2];
    const int i = blockIdx.x;            // 0..H-1: rows of W2o; i==H: b2o row
    const int j = threadIdx.x;           // 0..127
    const float* src = (i < H) ? (W2o + i * H2) : b2o;
    row[j] = src[j];
    __syncthreads();
    float acc = 0.f;
#pragma unroll 8
    for (int k = 0; k < H2; ++k) acc = fmaf(row[k], Wb[k * H2 + j], acc);
    if (i < H) W2of[i * H2 + j] = acc;
    else       b2of[j] = acc;
}

// ---------------- k1: prep — bf16 casts + weight transposes -----------------
// xb[m][k]   = bf16(x)                       (M x H)
// W1T[n][k]  = bf16(n<256 ? W1o[k][n] : W1d[k][n-256])   (512 x 256)
// W2T[n][k]  = bf16(n<128 ? W2of[k][n] : W2d[k][n-128])  (256 x 256)
// bias1[512] = [b1o|b1d], bias2[256] = [b2of|b2d]  (fp32)
__global__ void prep_kernel(const float* __restrict__ x,
                            const float* __restrict__ W1o, const float* __restrict__ W1d,
                            const float* __restrict__ b1o, const float* __restrict__ b1d,
                            const float* __restrict__ W2of, const float* __restrict__ b2of,
                            const float* __restrict__ W2d,  const float* __restrict__ b2d,
                            unsigned short* __restrict__ xb,
                            unsigned short* __restrict__ W1T,
                            unsigned short* __restrict__ W2T,
                            float* __restrict__ bias1, float* __restrict__ bias2)
{
    const int NX  = M * H;        // 1048576
    const int NW1 = 512 * H;      // 131072
    const int NW2 = 256 * H;      // 65536
    const int TOT = NX + NW1 + NW2 + 512 + 256;
    for (int i = blockIdx.x * blockDim.x + threadIdx.x; i < TOT;
         i += gridDim.x * blockDim.x) {
        if (i < NX) {
            xb[i] = f2bf(x[i]);
        } else if (i < NX + NW1) {
            const int j = i - NX, n = j >> 8, k = j & 255;
            const float v = (n < 256) ? W1o[k * H + n] : W1d[k * H + (n - 256)];
            W1T[j] = f2bf(v);
        } else if (i < NX + NW1 + NW2) {
            const int j = i - NX - NW1, n = j >> 8, k = j & 255;
            const float v = (n < 128) ? W2of[k * H2 + n] : W2d[k * H2 + (n - 128)];
            W2T[j] = f2bf(v);
        } else if (i < NX + NW1 + NW2 + 512) {
            const int j = i - NX - NW1 - NW2;
            bias1[j] = (j < 256) ? b1o[j] : b1d[j - 256];
        } else {
            const int j = i - NX - NW1 - NW2 - 512;
            bias2[j] = (j < 128) ? b2of[j] : b2d[j - 128];
        }
    }
}

// ---------------- MFMA 64x64 tile body, K=256, bf16 in / bf16 out -----------
// 4 waves; wave w owns output cols [16w,16w+16). Per K-chunk(32): 1 B-frag +
// 4 A-frag ds_read_b128 + 4 mfma. LDS rows padded to 40 shorts (80B) so all
// 16B reads stay aligned and bank groups are balanced.
template<bool RELU>
__device__ __forceinline__ void enc_body(
    const unsigned short* __restrict__ A, int lda,   // pre-offset to row0
    const unsigned short* __restrict__ Bt,           // pre-offset; ldb=256
    const float* __restrict__ bias,                  // pre-offset to col0
    unsigned short* __restrict__ C, int ldc)         // pre-offset to (row0,col0)
{
    __shared__ unsigned short Abuf[64 * 40];
    __shared__ unsigned short Bbuf[64 * 40];
    const int tid = threadIdx.x;
    const int w  = tid >> 6;
    const int l  = tid & 63;
    const int lr = tid >> 2;            // staging row 0..63
    const int lk = (tid & 3) * 8;       // staging k offset (shorts)

    uint4 aR = *(const uint4*)(A + (size_t)lr * lda + lk);
    uint4 bR = *(const uint4*)(Bt + (size_t)lr * 256 + lk);

    f32x4 z = {0.f, 0.f, 0.f, 0.f};
    f32x4 acc[4] = {z, z, z, z};

    for (int kc = 0; kc < 256; kc += 32) {
        if (kc) __syncthreads();
        *(uint4*)&Abuf[lr * 40 + lk] = aR;
        *(uint4*)&Bbuf[lr * 40 + lk] = bR;
        __syncthreads();
        if (kc + 32 < 256) {
            aR = *(const uint4*)(A + (size_t)lr * lda + kc + 32 + lk);
            bR = *(const uint4*)(Bt + (size_t)lr * 256 + kc + 32 + lk);
        }
        const int q8 = (l >> 4) * 8;
        const short8 bf = *(const short8*)&Bbuf[(w * 16 + (l & 15)) * 40 + q8];
#pragma unroll
        for (int it = 0; it < 4; ++it) {
            const short8 af = *(const short8*)&Abuf[(it * 16 + (l & 15)) * 40 + q8];
            acc[it] = __builtin_amdgcn_mfma_f32_16x16x32_bf16(af, bf, acc[it], 0, 0, 0);
        }
    }

    // epilogue: D col = lane&15, row = (lane>>4)*4 + reg  [m89/m91 verified]
    const int n  = w * 16 + (l & 15);
    const int r0 = (l >> 4) * 4;
    const float bn = bias[n];
#pragma unroll
    for (int it = 0; it < 4; ++it)
#pragma unroll
        for (int r = 0; r < 4; ++r) {
            float v = acc[it][r] + bn;
            if (RELU) v = fmaxf(v, 0.f);
            C[(size_t)(it * 16 + r0 + r) * ldc + n] = f2bf(v);
        }
}

// k2: h = relu(x @ [W1o|W1d] + bias1), bf16 out (M x 512). grid (8, 64)
__global__ __launch_bounds__(256) void enc1_kernel(
    const unsigned short* __restrict__ xb, const unsigned short* __restrict__ W1T,
    const float* __restrict__ bias1, unsigned short* __restrict__ h)
{
    const int bx = blockIdx.x, by = blockIdx.y;
    enc_body<true>(xb + (size_t)by * 64 * 256, 256,
                   W1T + (size_t)bx * 64 * 256,
                   bias1 + bx * 64,
                   h + (size_t)by * 64 * 512 + bx * 64, 512);
}

// k3: od = [oW | dd] = h_branch @ W2T + bias2, bf16 out (M x 256). grid (4, 64)
__global__ __launch_bounds__(256) void enc2_kernel(
    const unsigned short* __restrict__ h, const unsigned short* __restrict__ W2T,
    const float* __restrict__ bias2, unsigned short* __restrict__ od)
{
    const int bx = blockIdx.x, by = blockIdx.y;
    enc_body<false>(h + (size_t)by * 64 * 512 + (bx >> 1) * 256, 512,
                    W2T + (size_t)bx * 64 * 256,
                    bias2 + bx * 64,
                    od + (size_t)by * 64 * 256 + bx * 64, 256);
}

// ---------------- k4: scores (MFMA) + fused horizon expansion ---------------
// 64x64 score tile, grid (16,16,4) = 1024 blocks. K = 128 (4 chunks).
// S = oW @ dd^T: B-operand rows are dd rows (row-major-K) — no transpose.
__global__ __launch_bounds__(256) void k3_kernel(
    const unsigned short* __restrict__ od,
    const float* __restrict__ bbp, const float* __restrict__ wh,
    const float* __restrict__ bh, float* __restrict__ out)
{
    __shared__ unsigned short Abuf[64 * 40];
    __shared__ unsigned short Bbuf[64 * 40];
    const int tid = threadIdx.x;
    const int w  = tid >> 6;
    const int l  = tid & 63;
    const int lr = tid >> 2;
    const int lk = (tid & 3) * 8;
    const int b  = blockIdx.z;
    const int i0 = blockIdx.y * 64;
    const int j0 = blockIdx.x * 64;
    const unsigned short* Ab = od + ((size_t)b * N + i0) * 256;        // oW rows
    const unsigned short* Bb = od + ((size_t)b * N + j0) * 256 + 128;  // dd rows

    uint4 aR = *(const uint4*)(Ab + (size_t)lr * 256 + lk);
    uint4 bR = *(const uint4*)(Bb + (size_t)lr * 256 + lk);

    f32x4 z = {0.f, 0.f, 0.f, 0.f};
    f32x4 acc[4] = {z, z, z, z};

    for (int kc = 0; kc < H2; kc += 32) {
        if (kc) __syncthreads();
        *(uint4*)&Abuf[lr * 40 + lk] = aR;
        *(uint4*)&Bbuf[lr * 40 + lk] = bR;
        __syncthreads();
        if (kc + 32 < H2) {
            aR = *(const uint4*)(Ab + (size_t)lr * 256 + kc + 32 + lk);
            bR = *(const uint4*)(Bb + (size_t)lr * 256 + kc + 32 + lk);
        }
        const int q8 = (l >> 4) * 8;
        const short8 bf = *(const short8*)&Bbuf[(w * 16 + (l & 15)) * 40 + q8];
#pragma unroll
        for (int it = 0; it < 4; ++it) {
            const short8 af = *(const short8*)&Abuf[(it * 16 + (l & 15)) * 40 + q8];
            acc[it] = __builtin_amdgcn_mfma_f32_16x16x32_bf16(af, bf, acc[it], 0, 0, 0);
        }
    }

    const float bbv = bbp[0];
    float s[4][4];
#pragma unroll
    for (int it = 0; it < 4; ++it)
#pragma unroll
        for (int r = 0; r < 4; ++r) s[it][r] = acc[it][r] + bbv;

    const int jcol = j0 + w * 16 + (l & 15);
    const int r0   = (l >> 4) * 4;
    // out[((b*T+t)*N + i)*N + j]; each wave store = 4 rows x 64B full lines
#pragma unroll
    for (int t = 0; t < T; ++t) {
        const float wt = wh[t], bt = bh[t];
        float* ob = out + ((size_t)(b * T + t) * N + i0 + r0) * N + jcol;
#pragma unroll
        for (int it = 0; it < 4; ++it)
#pragma unroll
            for (int r = 0; r < 4; ++r)
                ob[(size_t)(it * 16 + r) * N] = fmaxf(fmaf(s[it][r], wt, bt), 0.f);
    }
}

extern "C" void kernel_launch(void* const* d_in, const int* in_sizes, int n_in,
                              void* d_out, int out_size, void* d_ws, size_t ws_size,
                              hipStream_t stream) {
    const float* x   = (const float*)d_in[0];
    const float* W1o = (const float*)d_in[1];
    const float* b1o = (const float*)d_in[2];
    const float* W2o = (const float*)d_in[3];
    const float* b2o = (const float*)d_in[4];
    const float* W1d = (const float*)d_in[5];
    const float* b1d = (const float*)d_in[6];
    const float* W2d = (const float*)d_in[7];
    const float* b2d = (const float*)d_in[8];
    const float* Wb  = (const float*)d_in[9];
    const float* bb  = (const float*)d_in[10];
    const float* wh  = (const float*)d_in[11];
    const float* bh  = (const float*)d_in[12];
    float* out = (float*)d_out;

    // workspace layout: fp32 first, then bf16 (all 16B-aligned)
    float* W2of  = (float*)d_ws;                    // 256*128
    float* b2of  = W2of + H * H2;                   // 128
    float* bias1 = b2of + H2;                       // 512
    float* bias2 = bias1 + 512;                     // 256
    unsigned short* xb  = (unsigned short*)(bias2 + 256);   // M*256
    unsigned short* W1T = xb + (size_t)M * H;               // 512*256
    unsigned short* W2T = W1T + 512 * H;                    // 256*256
    unsigned short* h   = W2T + 256 * H;                    // M*512
    unsigned short* od  = h + (size_t)M * 512;              // M*256 = [oW|dd]

    fold_wb_kernel<<<H + 1, H2, 0, stream>>>(W2o, b2o, Wb, W2of, b2of);

    prep_kernel<<<1024, 256, 0, stream>>>(x, W1o, W1d, b1o, b1d,
                                          W2of, b2of, W2d, b2d,
                                          xb, W1T, W2T, bias1, bias2);

    enc1_kernel<<<dim3(8, M / 64), 256, 0, stream>>>(xb, W1T, bias1, h);

    enc2_kernel<<<dim3(4, M / 64), 256, 0, stream>>>(h, W2T, bias2, od);

    k3_kernel<<<dim3(N / 64, N / 64, B), 256, 0, stream>>>(od, bb, wh, bh, out);
}